// Round 8
// baseline (442.040 us; speedup 1.0000x reference)
//
#include <hip/hip_runtime.h>
#include <hip/hip_bf16.h>
#include <math.h>

typedef __attribute__((ext_vector_type(4))) float f32x4;
typedef __attribute__((ext_vector_type(8))) short s16x8;
typedef unsigned short u16;
typedef unsigned int u32;

#define CDIM 384
#define PDIM 192
#define LDIM 4096
#define BSZ  16
#define MDIM 65536
#define KD   384
#define BM 128
#define BN 192
#define BK 32
#define NT (KD / BK)
#define ABUFE (BM * BK)   // 4096 u16 = 8 KB per A buffer (x3)
#define BBUFE (BN * BK)   // 6144 u16 = 12 KB per B buffer (x2)
#define EXS 100           // exchange stride (u16) for zg epilogue

__device__ __forceinline__ u16 f2bf(float f) {
    u32 x = __float_as_uint(f);
    x += 0x7fffu + ((x >> 16) & 1u);
    return (u16)(x >> 16);
}
__device__ __forceinline__ float bf2f(u16 v) {
    return __uint_as_float(((u32)v) << 16);
}
__device__ __forceinline__ float gelu_exact(float x) {   // setup only (cold)
    return 0.5f * x * (1.0f + erff(x * 0.7071067811865476f));
}
// tanh-form gelu as a single sigmoid: x * sigmoid(1.59577*x*(1+0.044715x^2))
// max abs err vs exact gelu ~2e-3 — far under bf16 epilogue noise here.
__device__ __forceinline__ float gelu_fast(float x) {
    float w = -1.5957691216f * x * (1.0f + 0.044715f * x * x);
    return x / (1.0f + __expf(w));
}
__device__ __forceinline__ void gld_lds16(const u16* g, u16* l) {
    __builtin_amdgcn_global_load_lds(
        (const __attribute__((address_space(1))) void*)g,
        (__attribute__((address_space(3))) void*)l, 16, 0, 0);
}

// XCD-chunked swizzle: consecutive work-ids land on the same XCD, and work
// is decoded n-fastest so the NY blocks sharing an A-panel are consecutive
// (same-XCD L2 reuse of the A panel). Bijective: nwg % 8 == 0 here.
__device__ __forceinline__ void swz_decode(int NY, int& mt, int& nt) {
    int bid = blockIdx.x + gridDim.x * blockIdx.y;
    int nwg = gridDim.x * gridDim.y;
    int cpx = nwg >> 3;
    int work = (bid & 7) * cpx + (bid >> 3);
    mt = work / NY;
    nt = work - mt * NY;
}

// ---------------- setup: build bf16 weights + lam_bar ----------------
__global__ __launch_bounds__(256) void k_setup(
    const float* __restrict__ Lambda, const float* __restrict__ Bmat,
    const float* __restrict__ Cmat, const float* __restrict__ log_step,
    const float* __restrict__ W_enc, const float* __restrict__ W_dec,
    u16* __restrict__ Wb, u16* __restrict__ Wc, u16* __restrict__ We,
    u16* __restrict__ Wd, float* __restrict__ lam_bar)
{
    int idx = blockIdx.x * 256 + threadIdx.x;
    if (idx < 73728) {                       // Wb: B_bar^T rows [2P][C]
        int p = idx / CDIM, c = idx % CDIM;
        float st  = expf(log_step[p]);
        float lre = Lambda[2*p], lim = Lambda[2*p+1];
        float el  = expf(lre * st);
        float lbr = el * cosf(lim * st);
        float lbi = el * sinf(lim * st);
        float dd  = lre*lre + lim*lim;
        float a = lbr - 1.0f, b = lbi;
        float cr = (a * lre + b * lim) / dd; // (lam_bar-1)/lam
        float ci = (b * lre - a * lim) / dd;
        float Br = Bmat[2*(p*CDIM + c)], Bi = Bmat[2*(p*CDIM + c) + 1];
        Wb[p*KD + c]          = f2bf(cr*Br - ci*Bi);
        Wb[(PDIM + p)*KD + c] = f2bf(cr*Bi + ci*Br);
    } else if (idx < 147456) {               // Wc: [C][2P], 2*mask folded, -im
        int e = idx - 73728;
        int h = e / PDIM, p = e % PDIM;
        float st  = expf(log_step[p]);
        float lim = Lambda[2*p+1];
        float freq = st * fabsf(lim) / 6.283185307179586f;
        float sc = (freq < 0.25f) ? 2.0f : 0.0f;
        Wc[h*KD + p]        = f2bf( sc * Cmat[2*(h*PDIM + p)]);
        Wc[h*KD + PDIM + p] = f2bf(-sc * Cmat[2*(h*PDIM + p) + 1]);
    } else if (idx < 442368) {               // We: W_enc [768][384]
        int e = idx - 147456;
        We[e] = f2bf(W_enc[e]);
    } else if (idx < 589824) {               // Wd: W_dec [384][384]
        int e = idx - 442368;
        Wd[e] = f2bf(W_dec[e]);
    } else if (idx < 590016) {               // lam_bar [P][2]
        int p = idx - 589824;
        float st  = expf(log_step[p]);
        float lre = Lambda[2*p], lim = Lambda[2*p+1];
        float el  = expf(lre * st);
        lam_bar[2*p]   = el * cosf(lim * st);
        lam_bar[2*p+1] = el * sinf(lim * st);
    }
}

// ---------------- LN1 + transpose: x[B,C,L] fp32 -> fx[M,C] bf16 ----------------
#define LNS 388
__global__ __launch_bounds__(256) void k_ln1(
    const float* __restrict__ x, const float* __restrict__ g,
    const float* __restrict__ bb, u16* __restrict__ fx)
{
    __shared__ float tile[32 * LNS];
    __shared__ float mu_sh[32], inv_sh[32];
    int b  = blockIdx.x >> 7;
    int l0 = (blockIdx.x & 127) * 32;
    int tid = threadIdx.x;
    const float* src = x + ((size_t)b * CDIM) * LDIM + l0;
    #pragma unroll
    for (int it = 0; it < 12; it++) {
        int s = it * 256 + tid;           // 3072 float4 slots
        int ch = s >> 3, k4 = s & 7;
        float4 v = *(const float4*)(src + (size_t)ch * LDIM + k4 * 4);
        float* t0 = tile + (k4 * 4) * LNS + ch;
        t0[0]       = v.x;
        t0[LNS]     = v.y;
        t0[2*LNS]   = v.z;
        t0[3*LNS]   = v.w;
    }
    __syncthreads();
    int j = tid >> 3, k = tid & 7;        // j: l-row 0..31, k: 8-way c-split
    float sum = 0.f, sq = 0.f;
    #pragma unroll
    for (int m = 0; m < 12; m++) {
        float4 v = *(const float4*)(tile + j * LNS + (k + 8*m) * 4);
        sum += v.x + v.y + v.z + v.w;
        sq  += v.x*v.x + v.y*v.y + v.z*v.z + v.w*v.w;
    }
    sum += __shfl_xor(sum, 1); sq += __shfl_xor(sq, 1);
    sum += __shfl_xor(sum, 2); sq += __shfl_xor(sq, 2);
    sum += __shfl_xor(sum, 4); sq += __shfl_xor(sq, 4);
    float mu  = sum * (1.0f / CDIM);
    float var = sq * (1.0f / CDIM) - mu * mu;
    float inv = rsqrtf(var + 1e-5f);
    if (k == 0) { mu_sh[j] = mu; inv_sh[j] = inv; }
    __syncthreads();
    u16* dst = fx + ((size_t)(b * LDIM + l0)) * CDIM;
    #pragma unroll
    for (int it = 0; it < 12; it++) {
        int s  = it * 256 + tid;          // 3072 slots of 4 channels
        int cq = s % 96, jj = s / 96;
        int c  = cq * 4;
        float m2 = mu_sh[jj], iv = inv_sh[jj];
        float4 gv = *(const float4*)(g + c);
        float4 bv = *(const float4*)(bb + c);
        float4 v  = *(const float4*)(tile + jj * LNS + c);
        ushort4 o;
        o.x = f2bf((v.x - m2) * iv * gv.x + bv.x);
        o.y = f2bf((v.y - m2) * iv * gv.y + bv.y);
        o.z = f2bf((v.z - m2) * iv * gv.z + bv.z);
        o.w = f2bf((v.w - m2) * iv * gv.w + bv.w);
        *(ushort4*)(dst + (size_t)jj * CDIM + c) = o;
    }
}

// --------- 128x192 GEMM core: wave tile 64x96, A 3-buf / B 2-buf -------------
// LDS-read-BW lever: FLOP per LDS byte = Wm*Wn/(Wm+Wn). 64x64 gave 32 (the
// ~25-29% MfmaUtil plateau of r1-r7); 64x96 gives 38.4 and 24 MFMA per
// barrier-protocol instance (+50%). acc[4][6] = 96 AGPR + ~70 arch VGPR ->
// 2 waves/SIMD (r7 showed 4-vs-2 waves is worth ~nothing, so trade it).
// Queue discipline (per wave): prologue A(0):2, B(0):3, A(1):2; per-iter
// issue B(t+1):3 then A(t+2):2. At iter-t wait queue = [A(t):2,B(t):3,
// A(t+1):2] -> s_waitcnt vmcnt(2) retires tile t, A(t+1) rides the barrier.
// Trailing lgkmcnt(0)+sched_barrier(0) closes the rule-18 MFMA-sink race
// (each buffer is rewritten one iteration after its last ds_read).
template<bool SWAP>
__device__ __forceinline__ void gemm_core(
    const u16* __restrict__ A, int lda, const u16* __restrict__ Bw,
    int m0, int n0, u16* a_sh, u16* b_sh, f32x4 acc[4][6])
{
    const int tid  = threadIdx.x;
    const int w    = tid >> 6, lane = tid & 63;
    const int t16  = lane & 15, quad = lane >> 4;
    const int wm   = w >> 1,   wn   = w & 1;
    const int lr  = lane >> 2;                       // row within 16-row issue
    const int cbg = (lane & 3) ^ ((lane >> 3) & 3);  // swizzled col-block
    const u16* gA0 = A  + (size_t)(m0 + w*32 + lr) * lda + cbg*8;
    const u16* gA1 = gA0 + (size_t)16 * lda;
    const u16* gB0 = Bw + (size_t)(n0 + w*48 + lr) * KD + cbg*8;
    const u16* gB1 = gB0 + (size_t)16 * KD;
    const u16* gB2 = gB0 + (size_t)32 * KD;
    u16* lA0 = a_sh + (w*32) * BK;                   // wave-uniform LDS bases
    u16* lA1 = lA0 + 16*BK;
    u16* lB0 = b_sh + (w*48) * BK;
    u16* lB1 = lB0 + 16*BK;
    u16* lB2 = lB0 + 32*BK;
    const int pos = (quad ^ ((t16 >> 1) & 3)) * 8;
    const u16* ard = a_sh + (wm*64 + t16) * BK + pos;
    const u16* brd = b_sh + (wn*96 + t16) * BK + pos;
    #pragma unroll
    for (int i = 0; i < 4; i++)
        #pragma unroll
        for (int j = 0; j < 6; j++) acc[i][j] = (f32x4){0.f,0.f,0.f,0.f};
    // prologue: A(0), B(0), A(1) — queue order matters for vmcnt counting
    gld_lds16(gA0, lA0);
    gld_lds16(gA1, lA1);
    gld_lds16(gB0, lB0);
    gld_lds16(gB1, lB1);
    gld_lds16(gB2, lB2);
    gld_lds16(gA0 + BK, lA0 + ABUFE);
    gld_lds16(gA1 + BK, lA1 + ABUFE);
    #pragma unroll
    for (int t = 0; t < NT; ++t) {
        if (t < NT - 1) asm volatile("s_waitcnt vmcnt(2)" ::: "memory");
        else            asm volatile("s_waitcnt vmcnt(0)" ::: "memory");
        __builtin_amdgcn_s_barrier();
        __builtin_amdgcn_sched_barrier(0);
        if (t + 1 < NT) {                 // B(t+1) first: stays older than A(t+2)
            const int kb = (t + 1) * BK, bo = ((t + 1) & 1) * BBUFE;
            gld_lds16(gB0 + kb, lB0 + bo);
            gld_lds16(gB1 + kb, lB1 + bo);
            gld_lds16(gB2 + kb, lB2 + bo);
        }
        if (t + 2 < NT) {
            const int kb = (t + 2) * BK, ao = ((t + 2) % 3) * ABUFE;
            gld_lds16(gA0 + kb, lA0 + ao);
            gld_lds16(gA1 + kb, lA1 + ao);
        }
        __builtin_amdgcn_sched_barrier(0);
        const u16* ac = ard + (t % 3) * ABUFE;
        const u16* bc = brd + (t & 1) * BBUFE;
        s16x8 bfr[6];
        #pragma unroll
        for (int j = 0; j < 6; j++) bfr[j] = *(const s16x8*)(bc + j*16*BK);
        __builtin_amdgcn_s_setprio(1);
        #pragma unroll
        for (int i = 0; i < 4; i++) {
            s16x8 af = *(const s16x8*)(ac + i*16*BK);
            #pragma unroll
            for (int j = 0; j < 6; j++) {
                if (SWAP)
                    acc[i][j] = __builtin_amdgcn_mfma_f32_16x16x32_bf16(bfr[j], af, acc[i][j], 0,0,0);
                else
                    acc[i][j] = __builtin_amdgcn_mfma_f32_16x16x32_bf16(af, bfr[j], acc[i][j], 0,0,0);
            }
        }
        __builtin_amdgcn_s_setprio(0);
        asm volatile("s_waitcnt lgkmcnt(0)" ::: "memory");
        __builtin_amdgcn_sched_barrier(0);
    }
}

// ---------------- GEMM kernels with fused epilogues ----------------
__global__ __launch_bounds__(256) void k_gemm_bu(
    const u16* __restrict__ fx, const u16* __restrict__ Wb, u16* __restrict__ Bu)
{
    __shared__ __align__(16) u16 a_sh[3*ABUFE], b_sh[2*BBUFE];
    int mt, nt;
    swz_decode(gridDim.y, mt, nt);
    int m0 = mt * BM, n0 = nt * BN;
    f32x4 acc[4][6];
    gemm_core<false>(fx, CDIM, Wb, m0, n0, a_sh, b_sh, acc);
    int lane = threadIdx.x & 63, w = threadIdx.x >> 6;
    int t16 = lane & 15, quad = lane >> 4, wm = w >> 1, wn = w & 1;
    #pragma unroll
    for (int i = 0; i < 4; i++)
        #pragma unroll
        for (int j = 0; j < 6; j++)
            #pragma unroll
            for (int rr = 0; rr < 4; rr++) {
                int m = m0 + wm*64 + i*16 + quad*4 + rr;
                int n = n0 + wn*96 + j*16 + t16;
                Bu[(size_t)m * CDIM + n] = f2bf(acc[i][j][rr]);
            }
}

__global__ __launch_bounds__(256) void k_gemm_y(
    const u16* __restrict__ xs, const u16* __restrict__ Wc,
    const u16* __restrict__ fx, const float* __restrict__ Dv, u16* __restrict__ y)
{
    __shared__ __align__(16) u16 a_sh[3*ABUFE], b_sh[2*BBUFE];
    int mt, nt;
    swz_decode(gridDim.y, mt, nt);
    int m0 = mt * BM, n0 = nt * BN;
    f32x4 acc[4][6];
    gemm_core<false>(xs, CDIM, Wc, m0, n0, a_sh, b_sh, acc);
    int lane = threadIdx.x & 63, w = threadIdx.x >> 6;
    int t16 = lane & 15, quad = lane >> 4, wm = w >> 1, wn = w & 1;
    float dv[6];
    #pragma unroll
    for (int j = 0; j < 6; j++) dv[j] = Dv[n0 + wn*96 + j*16 + t16];
    #pragma unroll
    for (int i = 0; i < 4; i++)
        #pragma unroll
        for (int j = 0; j < 6; j++)
            #pragma unroll
            for (int rr = 0; rr < 4; rr++) {
                int m = m0 + wm*64 + i*16 + quad*4 + rr;
                int n = n0 + wn*96 + j*16 + t16;
                float fxv = bf2f(fx[(size_t)m * CDIM + n]);
                float v = acc[i][j][rr] + dv[j] * fxv;
                y[(size_t)m * CDIM + n] = f2bf(gelu_fast(v) + fxv);
            }
}

// z-GEMM with fused GEGLU: block computes z1 cols [c0,c0+96) and z2 cols
// [384+c0, 384+c0+96); B-tile rows 0..95 = z1 (We rows c0+r), rows 96..191
// = z2 (We rows 384+c0+r-96). wn=1 waves gelu their z2 tile into LDS;
// wn=0 waves multiply and store zg[M,384] bf16.
__global__ __launch_bounds__(256) void k_gemm_zg(
    const u16* __restrict__ fy, const u16* __restrict__ We, u16* __restrict__ zg)
{
    __shared__ __align__(16) u16 sh[3*ABUFE + 2*BBUFE];  // 48 KB; reused as exchange (needs 128*EXS)
    u16* a_sh = sh;
    u16* b_sh = sh + 3*ABUFE;
    const int tid = threadIdx.x;
    const int w = tid >> 6, lane = tid & 63;
    const int t16 = lane & 15, quad = lane >> 4;
    const int wm = w >> 1, wn = w & 1;
    int mt, nt;
    swz_decode(gridDim.y, mt, nt);
    const int m0 = mt * BM;
    const int c0 = nt * 96;
    const int lr  = lane >> 2;
    const int cbg = (lane & 3) ^ ((lane >> 3) & 3);
    const u16* gA0 = fy + (size_t)(m0 + w*32 + lr) * CDIM + cbg*8;
    const u16* gA1 = gA0 + (size_t)16 * CDIM;
    int brow = (w < 2) ? (c0 + w*48) : (384 + c0 + (w - 2)*48);
    const u16* gB0 = We + (size_t)(brow + lr) * KD + cbg*8;
    const u16* gB1 = gB0 + (size_t)16 * KD;
    const u16* gB2 = gB0 + (size_t)32 * KD;
    u16* lA0 = a_sh + (w*32) * BK;
    u16* lA1 = lA0 + 16*BK;
    u16* lB0 = b_sh + (w*48) * BK;
    u16* lB1 = lB0 + 16*BK;
    u16* lB2 = lB0 + 32*BK;
    const int pos = (quad ^ ((t16 >> 1) & 3)) * 8;
    const u16* ard = a_sh + (wm*64 + t16) * BK + pos;
    const u16* brd = b_sh + (wn*96 + t16) * BK + pos;
    f32x4 acc[4][6];
    #pragma unroll
    for (int i = 0; i < 4; i++)
        #pragma unroll
        for (int j = 0; j < 6; j++) acc[i][j] = (f32x4){0.f,0.f,0.f,0.f};
    // prologue: A(0), B(0), A(1)
    gld_lds16(gA0, lA0);
    gld_lds16(gA1, lA1);
    gld_lds16(gB0, lB0);
    gld_lds16(gB1, lB1);
    gld_lds16(gB2, lB2);
    gld_lds16(gA0 + BK, lA0 + ABUFE);
    gld_lds16(gA1 + BK, lA1 + ABUFE);
    #pragma unroll
    for (int t = 0; t < NT; ++t) {
        if (t < NT - 1) asm volatile("s_waitcnt vmcnt(2)" ::: "memory");
        else            asm volatile("s_waitcnt vmcnt(0)" ::: "memory");
        __builtin_amdgcn_s_barrier();
        __builtin_amdgcn_sched_barrier(0);
        if (t + 1 < NT) {
            const int kb = (t + 1) * BK, bo = ((t + 1) & 1) * BBUFE;
            gld_lds16(gB0 + kb, lB0 + bo);
            gld_lds16(gB1 + kb, lB1 + bo);
            gld_lds16(gB2 + kb, lB2 + bo);
        }
        if (t + 2 < NT) {
            const int kb = (t + 2) * BK, ao = ((t + 2) % 3) * ABUFE;
            gld_lds16(gA0 + kb, lA0 + ao);
            gld_lds16(gA1 + kb, lA1 + ao);
        }
        __builtin_amdgcn_sched_barrier(0);
        const u16* ac = ard + (t % 3) * ABUFE;
        const u16* bc = brd + (t & 1) * BBUFE;
        s16x8 bfr[6];
        #pragma unroll
        for (int j = 0; j < 6; j++) bfr[j] = *(const s16x8*)(bc + j*16*BK);
        __builtin_amdgcn_s_setprio(1);
        #pragma unroll
        for (int i = 0; i < 4; i++) {
            s16x8 af = *(const s16x8*)(ac + i*16*BK);
            #pragma unroll
            for (int j = 0; j < 6; j++)
                acc[i][j] = __builtin_amdgcn_mfma_f32_16x16x32_bf16(af, bfr[j], acc[i][j], 0,0,0);
        }
        __builtin_amdgcn_s_setprio(0);
        asm volatile("s_waitcnt lgkmcnt(0)" ::: "memory");
        __builtin_amdgcn_sched_barrier(0);
    }
    __syncthreads();                       // all LDS frag reads done; reuse as exchange
    if (wn == 1) {
        #pragma unroll
        for (int i = 0; i < 4; i++)
            #pragma unroll
            for (int j = 0; j < 6; j++)
                #pragma unroll
                for (int rr = 0; rr < 4; rr++) {
                    int m = wm*64 + i*16 + quad*4 + rr;
                    int c = j*16 + t16;
                    sh[m*EXS + c] = f2bf(gelu_fast(acc[i][j][rr]));
                }
    }
    __syncthreads();
    if (wn == 0) {
        #pragma unroll
        for (int i = 0; i < 4; i++)
            #pragma unroll
            for (int j = 0; j < 6; j++)
                #pragma unroll
                for (int rr = 0; rr < 4; rr++) {
                    int m = wm*64 + i*16 + quad*4 + rr;
                    int c = j*16 + t16;
                    float gv = bf2f(sh[m*EXS + c]);
                    zg[(size_t)(m0 + m) * CDIM + c0 + c] = f2bf(acc[i][j][rr] * gv);
                }
    }
}

__global__ __launch_bounds__(256) void k_gemm_out(
    const u16* __restrict__ zg, const u16* __restrict__ Wd,
    const u16* __restrict__ fy, float* __restrict__ out)
{
    __shared__ __align__(16) u16 a_sh[3*ABUFE], b_sh[2*BBUFE];
    int mt, nt;
    swz_decode(gridDim.y, mt, nt);
    int m0 = mt * BM, n0 = nt * BN;
    f32x4 acc[4][6];
    gemm_core<true>(zg, CDIM, Wd, m0, n0, a_sh, b_sh, acc);
    int lane = threadIdx.x & 63, w = threadIdx.x >> 6;
    int t16 = lane & 15, quad = lane >> 4, wm = w >> 1, wn = w & 1;
    int b = m0 >> 12;
    #pragma unroll
    for (int i = 0; i < 4; i++)
        #pragma unroll
        for (int j = 0; j < 6; j++)
            #pragma unroll
            for (int rr = 0; rr < 4; rr++) {
                int nn = n0 + wn*96 + j*16 + quad*4 + rr;
                int mm = m0 + wm*64 + i*16 + t16;
                float fyv = bf2f(fy[(size_t)mm * CDIM + nn]);
                int l = mm & 4095;
                out[((size_t)(b * CDIM + nn)) * LDIM + l] = acc[i][j][rr] + fyv;
            }
}

// ---------------- chunked complex scan over L (chunk=64, 64 chunks/b) ----------------
__global__ __launch_bounds__(192) void k_scan_a(
    const u16* __restrict__ Bu, const float* __restrict__ lam_bar,
    float* __restrict__ summ)
{
    int b = blockIdx.x >> 6, ch = blockIdx.x & 63;
    int p = threadIdx.x;
    float lr = lam_bar[2*p], li = lam_bar[2*p+1];
    float xr = 0.f, xi = 0.f;
    const u16* base = Bu + (size_t)(b * LDIM + ch * 64) * CDIM;
    #pragma unroll 8
    for (int i = 0; i < 64; i++) {
        float br = bf2f(base[(size_t)i * CDIM + p]);
        float bi = bf2f(base[(size_t)i * CDIM + PDIM + p]);
        float nr = lr * xr - li * xi + br;
        float ni = lr * xi + li * xr + bi;
        xr = nr; xi = ni;
    }
    size_t o = (size_t)(b * 64 + ch) * CDIM + p;
    summ[o] = xr;
    summ[o + PDIM] = xi;
}

__global__ __launch_bounds__(256) void k_scan_b(
    const float* __restrict__ lam_bar, float* __restrict__ summ)
{
    int id = blockIdx.x * 256 + threadIdx.x;
    if (id >= BSZ * PDIM) return;
    int b = id / PDIM, p = id % PDIM;
    float ar = lam_bar[2*p], ai = lam_bar[2*p+1];
    #pragma unroll
    for (int s = 0; s < 6; s++) {       // lam_bar^64
        float nr = ar * ar - ai * ai, ni = 2.f * ar * ai;
        ar = nr; ai = ni;
    }
    float cr = 0.f, ci = 0.f;
    #pragma unroll 4
    for (int ch = 0; ch < 64; ch++) {
        size_t o = (size_t)(b * 64 + ch) * CDIM + p;
        float sr = summ[o], si = summ[o + PDIM];
        summ[o] = cr; summ[o + PDIM] = ci;   // exclusive carry-in
        float nr = ar * cr - ai * ci + sr;
        float ni = ar * ci + ai * cr + si;
        cr = nr; ci = ni;
    }
}

__global__ __launch_bounds__(192) void k_scan_c(
    u16* __restrict__ Bu, const float* __restrict__ lam_bar,
    const float* __restrict__ summ)
{
    int b = blockIdx.x >> 6, ch = blockIdx.x & 63;
    int p = threadIdx.x;
    float lr = lam_bar[2*p], li = lam_bar[2*p+1];
    size_t oc = (size_t)(b * 64 + ch) * CDIM + p;
    float xr = summ[oc], xi = summ[oc + PDIM];
    u16* base = Bu + (size_t)(b * LDIM + ch * 64) * CDIM;
    #pragma unroll 8
    for (int i = 0; i < 64; i++) {
        float br = bf2f(base[(size_t)i * CDIM + p]);
        float bi = bf2f(base[(size_t)i * CDIM + PDIM + p]);
        float nr = lr * xr - li * xi + br;
        float ni = lr * xi + li * xr + bi;
        xr = nr; xi = ni;
        base[(size_t)i * CDIM + p] = f2bf(xr);
        base[(size_t)i * CDIM + PDIM + p] = f2bf(xi);
    }
}

// ---------------- LN2 (rows contiguous, bf16 in/out, packed u32 loads) -------
__global__ __launch_bounds__(256) void k_ln2(
    const u16* __restrict__ y, const float* __restrict__ g,
    const float* __restrict__ bb, u16* __restrict__ fy)
{
    int w = threadIdx.x >> 6, lane = threadIdx.x & 63;
    size_t m = (size_t)blockIdx.x * 4 + w;
    const u16* row = y + m * CDIM;
    float v[6];
    float sum = 0.f, sq = 0.f;
    #pragma unroll
    for (int i = 0; i < 3; i++) {
        u32 pk = *(const u32*)(row + lane * 2 + 128 * i);
        float a = bf2f((u16)pk), b2 = bf2f((u16)(pk >> 16));
        v[2*i] = a; v[2*i+1] = b2;
        sum += a + b2; sq += a*a + b2*b2;
    }
    #pragma unroll
    for (int o = 1; o < 64; o <<= 1) {
        sum += __shfl_xor(sum, o); sq += __shfl_xor(sq, o);
    }
    float mu  = sum * (1.0f / CDIM);
    float var = sq * (1.0f / CDIM) - mu * mu;
    float inv = rsqrtf(var + 1e-5f);
    u16* dst = fy + m * CDIM;
    #pragma unroll
    for (int i = 0; i < 3; i++) {
        int c = lane * 2 + 128 * i;
        float2 gv = *(const float2*)(g + c);
        float2 bv = *(const float2*)(bb + c);
        u16 o0 = f2bf((v[2*i]   - mu) * inv * gv.x + bv.x);
        u16 o1 = f2bf((v[2*i+1] - mu) * inv * gv.y + bv.y);
        *(u32*)(dst + c) = (u32)o0 | ((u32)o1 << 16);
    }
}

extern "C" void kernel_launch(void* const* d_in, const int* in_sizes, int n_in,
                              void* d_out, int out_size, void* d_ws, size_t ws_size,
                              hipStream_t stream)
{
    const float* x        = (const float*)d_in[0];
    const float* ln1_g    = (const float*)d_in[1];
    const float* ln1_b    = (const float*)d_in[2];
    const float* Lambda   = (const float*)d_in[3];
    const float* Bmat     = (const float*)d_in[4];
    const float* Cmat     = (const float*)d_in[5];
    const float* Dvec     = (const float*)d_in[6];
    const float* log_step = (const float*)d_in[7];
    const float* ln2_g    = (const float*)d_in[8];
    const float* ln2_b    = (const float*)d_in[9];
    const float* W_enc    = (const float*)d_in[10];
    const float* W_dec    = (const float*)d_in[11];

    char* ws = (char*)d_ws;
    const size_t HBF = (size_t)MDIM * CDIM * 2;    // 50,331,648 B (bf16 [M,384])
    u16* fx = (u16*)(ws);                          // fx bf16
    u16* fy = (u16*)(ws + HBF);                    // fy bf16
    u16* bu = (u16*)(ws + 2 * HBF);                // Bu/xs bf16 [M,384]
    u16* zg = (u16*)(ws + 2 * HBF);                // zg bf16 [M,384] (aliases bu; bu dead)
    char* wbase = ws + 3 * HBF;
    u16* Wb = (u16*)(wbase);
    u16* Wc = (u16*)(wbase + 294912);
    u16* We = (u16*)(wbase + 589824);
    u16* Wd = (u16*)(wbase + 1179648);
    float* lam_bar = (float*)(wbase + 1474560);
    float* summ    = (float*)(wbase + 1476096);    // 16*64*384 fp32
    u16* yb  = (u16*)d_out;                        // y bf16 scratch inside d_out
    float* out = (float*)d_out;

    k_setup<<<2305, 256, 0, stream>>>(Lambda, Bmat, Cmat, log_step, W_enc, W_dec,
                                      Wb, Wc, We, Wd, lam_bar);
    k_ln1<<<2048, 256, 0, stream>>>(x, ln1_g, ln1_b, fx);
    k_gemm_bu<<<dim3(512, 2), 256, 0, stream>>>(fx, Wb, bu);
    k_scan_a<<<1024, 192, 0, stream>>>(bu, lam_bar, summ);
    k_scan_b<<<12, 256, 0, stream>>>(lam_bar, summ);
    k_scan_c<<<1024, 192, 0, stream>>>(bu, lam_bar, summ);
    k_gemm_y<<<dim3(512, 2), 256, 0, stream>>>(bu, Wc, fx, Dvec, yb);
    k_ln2<<<16384, 256, 0, stream>>>(yb, ln2_g, ln2_b, fy);
    k_gemm_zg<<<dim3(512, 4), 256, 0, stream>>>(fy, We, zg);
    k_gemm_out<<<dim3(512, 2), 256, 0, stream>>>(zg, Wd, fy, out);
}

// Round 9
// 427.973 us; speedup vs baseline: 1.0329x; 1.0329x over previous
//
#include <hip/hip_runtime.h>
#include <hip/hip_bf16.h>
#include <math.h>

typedef __attribute__((ext_vector_type(4))) float f32x4;
typedef __attribute__((ext_vector_type(8))) short s16x8;
typedef unsigned short u16;
typedef unsigned int u32;

#define CDIM 384
#define PDIM 192
#define LDIM 4096
#define BSZ  16
#define MDIM 65536
#define KD   384
#define BM 128
#define BN 128
#define BK 32
#define NT (KD / BK)
#define BUFE (BM * BK)    // 4096 u16 = 8 KB per LDS buffer (A x3, B x2)

__device__ __forceinline__ u16 f2bf(float f) {
    u32 x = __float_as_uint(f);
    x += 0x7fffu + ((x >> 16) & 1u);
    return (u16)(x >> 16);
}
__device__ __forceinline__ float bf2f(u16 v) {
    return __uint_as_float(((u32)v) << 16);
}
__device__ __forceinline__ float gelu_exact(float x) {   // setup only (cold)
    return 0.5f * x * (1.0f + erff(x * 0.7071067811865476f));
}
// tanh-form gelu as a single sigmoid: x * sigmoid(1.59577*x*(1+0.044715x^2))
// max abs err vs exact gelu ~2e-3 — far under bf16 epilogue noise here.
__device__ __forceinline__ float gelu_fast(float x) {
    float w = -1.5957691216f * x * (1.0f + 0.044715f * x * x);
    return x / (1.0f + __expf(w));
}
__device__ __forceinline__ void gld_lds16(const u16* g, u16* l) {
    __builtin_amdgcn_global_load_lds(
        (const __attribute__((address_space(1))) void*)g,
        (__attribute__((address_space(3))) void*)l, 16, 0, 0);
}

// XCD-chunked swizzle: consecutive work-ids land on the same XCD, and work
// is decoded n-fastest so the NY blocks sharing an A-panel are consecutive
// (same-XCD L2 reuse of the A panel). Bijective: nwg % 8 == 0 here.
__device__ __forceinline__ void swz_decode(int NY, int& mt, int& nt) {
    int bid = blockIdx.x + gridDim.x * blockIdx.y;
    int nwg = gridDim.x * gridDim.y;
    int cpx = nwg >> 3;
    int work = (bid & 7) * cpx + (bid >> 3);
    mt = work / NY;
    nt = work - mt * NY;
}

// ---------------- setup: build bf16 weights + lam_bar ----------------
__global__ __launch_bounds__(256) void k_setup(
    const float* __restrict__ Lambda, const float* __restrict__ Bmat,
    const float* __restrict__ Cmat, const float* __restrict__ log_step,
    const float* __restrict__ W_enc, const float* __restrict__ W_dec,
    u16* __restrict__ Wb, u16* __restrict__ Wc, u16* __restrict__ We,
    u16* __restrict__ Wd, float* __restrict__ lam_bar)
{
    int idx = blockIdx.x * 256 + threadIdx.x;
    if (idx < 73728) {                       // Wb: B_bar^T rows [2P][C]
        int p = idx / CDIM, c = idx % CDIM;
        float st  = expf(log_step[p]);
        float lre = Lambda[2*p], lim = Lambda[2*p+1];
        float el  = expf(lre * st);
        float lbr = el * cosf(lim * st);
        float lbi = el * sinf(lim * st);
        float dd  = lre*lre + lim*lim;
        float a = lbr - 1.0f, b = lbi;
        float cr = (a * lre + b * lim) / dd; // (lam_bar-1)/lam
        float ci = (b * lre - a * lim) / dd;
        float Br = Bmat[2*(p*CDIM + c)], Bi = Bmat[2*(p*CDIM + c) + 1];
        Wb[p*KD + c]          = f2bf(cr*Br - ci*Bi);
        Wb[(PDIM + p)*KD + c] = f2bf(cr*Bi + ci*Br);
    } else if (idx < 147456) {               // Wc: [C][2P], 2*mask folded, -im
        int e = idx - 73728;
        int h = e / PDIM, p = e % PDIM;
        float st  = expf(log_step[p]);
        float lim = Lambda[2*p+1];
        float freq = st * fabsf(lim) / 6.283185307179586f;
        float sc = (freq < 0.25f) ? 2.0f : 0.0f;
        Wc[h*KD + p]        = f2bf( sc * Cmat[2*(h*PDIM + p)]);
        Wc[h*KD + PDIM + p] = f2bf(-sc * Cmat[2*(h*PDIM + p) + 1]);
    } else if (idx < 442368) {               // We: W_enc [768][384]
        int e = idx - 147456;
        We[e] = f2bf(W_enc[e]);
    } else if (idx < 589824) {               // Wd: W_dec [384][384]
        int e = idx - 442368;
        Wd[e] = f2bf(W_dec[e]);
    } else if (idx < 590016) {               // lam_bar [P][2]
        int p = idx - 589824;
        float st  = expf(log_step[p]);
        float lre = Lambda[2*p], lim = Lambda[2*p+1];
        float el  = expf(lre * st);
        lam_bar[2*p]   = el * cosf(lim * st);
        lam_bar[2*p+1] = el * sinf(lim * st);
    }
}

// ---------------- LN1 + transpose: x[B,C,L] fp32 -> fx[M,C] bf16 ----------------
#define LNS 388
__global__ __launch_bounds__(256) void k_ln1(
    const float* __restrict__ x, const float* __restrict__ g,
    const float* __restrict__ bb, u16* __restrict__ fx)
{
    __shared__ float tile[32 * LNS];
    __shared__ float mu_sh[32], inv_sh[32];
    int b  = blockIdx.x >> 7;
    int l0 = (blockIdx.x & 127) * 32;
    int tid = threadIdx.x;
    const float* src = x + ((size_t)b * CDIM) * LDIM + l0;
    #pragma unroll
    for (int it = 0; it < 12; it++) {
        int s = it * 256 + tid;           // 3072 float4 slots
        int ch = s >> 3, k4 = s & 7;
        float4 v = *(const float4*)(src + (size_t)ch * LDIM + k4 * 4);
        float* t0 = tile + (k4 * 4) * LNS + ch;
        t0[0]       = v.x;
        t0[LNS]     = v.y;
        t0[2*LNS]   = v.z;
        t0[3*LNS]   = v.w;
    }
    __syncthreads();
    int j = tid >> 3, k = tid & 7;        // j: l-row 0..31, k: 8-way c-split
    float sum = 0.f, sq = 0.f;
    #pragma unroll
    for (int m = 0; m < 12; m++) {
        float4 v = *(const float4*)(tile + j * LNS + (k + 8*m) * 4);
        sum += v.x + v.y + v.z + v.w;
        sq  += v.x*v.x + v.y*v.y + v.z*v.z + v.w*v.w;
    }
    sum += __shfl_xor(sum, 1); sq += __shfl_xor(sq, 1);
    sum += __shfl_xor(sum, 2); sq += __shfl_xor(sq, 2);
    sum += __shfl_xor(sum, 4); sq += __shfl_xor(sq, 4);
    float mu  = sum * (1.0f / CDIM);
    float var = sq * (1.0f / CDIM) - mu * mu;
    float inv = rsqrtf(var + 1e-5f);
    if (k == 0) { mu_sh[j] = mu; inv_sh[j] = inv; }
    __syncthreads();
    u16* dst = fx + ((size_t)(b * LDIM + l0)) * CDIM;
    #pragma unroll
    for (int it = 0; it < 12; it++) {
        int s  = it * 256 + tid;          // 3072 slots of 4 channels
        int cq = s % 96, jj = s / 96;
        int c  = cq * 4;
        float m2 = mu_sh[jj], iv = inv_sh[jj];
        float4 gv = *(const float4*)(g + c);
        float4 bv = *(const float4*)(bb + c);
        float4 v  = *(const float4*)(tile + jj * LNS + c);
        ushort4 o;
        o.x = f2bf((v.x - m2) * iv * gv.x + bv.x);
        o.y = f2bf((v.y - m2) * iv * gv.y + bv.y);
        o.z = f2bf((v.z - m2) * iv * gv.z + bv.z);
        o.w = f2bf((v.w - m2) * iv * gv.w + bv.w);
        *(ushort4*)(dst + (size_t)jj * CDIM + c) = o;
    }
}

// ------------- 128x128 GEMM core: A 3-buf / B 2-buf, reg-slim, 4 waves/SIMD ---
// r7 structure (best measured). Queue discipline: prologue A(0):2, B(0):2,
// A(1):2; per-iter issue B(t+1):2 then A(t+2):2. At iter-t wait the queue is
// [A(t),B(t),A(t+1)] -> s_waitcnt vmcnt(2) retires tile t while A(t+1) rides
// the barrier (B 1-step cover: L2-hot weights; A 2-step: L3-latency stream).
// Trailing lgkmcnt(0)+sched_barrier(0) closes the rule-18 MFMA-sink race
// (each buffer is rewritten one iteration after its last ds_read).
template<bool SWAP>
__device__ __forceinline__ void gemm_core(
    const u16* __restrict__ A, int lda, const u16* __restrict__ Bw,
    int m0, int n0, u16* a_sh, u16* b_sh, f32x4 acc[4][4])
{
    const int tid  = threadIdx.x;
    const int w    = tid >> 6, lane = tid & 63;
    const int t16  = lane & 15, quad = lane >> 4;
    const int wm   = w >> 1,   wn   = w & 1;
    const int lr  = lane >> 2;                       // row within 16-row issue
    const int cbg = (lane & 3) ^ ((lane >> 3) & 3);  // swizzled col-block
    const u16* gA0 = A  + (size_t)(m0 + w*32 + lr) * lda + cbg*8;
    const u16* gA1 = gA0 + (size_t)16 * lda;
    const u16* gB0 = Bw + (size_t)(n0 + w*32 + lr) * KD + cbg*8;
    const u16* gB1 = gB0 + (size_t)16 * KD;
    u16* lA0 = a_sh + (w*32) * BK;                   // wave-uniform LDS bases
    u16* lA1 = lA0 + 16*BK;
    u16* lB0 = b_sh + (w*32) * BK;
    u16* lB1 = lB0 + 16*BK;
    const int pos = (quad ^ ((t16 >> 1) & 3)) * 8;
    const u16* ard = a_sh + (wm*64 + t16) * BK + pos;
    const u16* brd = b_sh + (wn*64 + t16) * BK + pos;
    #pragma unroll
    for (int i = 0; i < 4; i++)
        #pragma unroll
        for (int j = 0; j < 4; j++) acc[i][j] = (f32x4){0.f,0.f,0.f,0.f};
    // prologue: A(0), B(0), A(1) — queue order matters for vmcnt counting
    gld_lds16(gA0, lA0);
    gld_lds16(gA1, lA1);
    gld_lds16(gB0, lB0);
    gld_lds16(gB1, lB1);
    gld_lds16(gA0 + BK, lA0 + BUFE);
    gld_lds16(gA1 + BK, lA1 + BUFE);
    #pragma unroll
    for (int t = 0; t < NT; ++t) {
        if (t < NT - 1) asm volatile("s_waitcnt vmcnt(2)" ::: "memory");
        else            asm volatile("s_waitcnt vmcnt(0)" ::: "memory");
        __builtin_amdgcn_s_barrier();
        __builtin_amdgcn_sched_barrier(0);
        if (t + 1 < NT) {                 // B(t+1) first: stays older than A(t+2)
            const int kb = (t + 1) * BK, bo = ((t + 1) & 1) * BUFE;
            gld_lds16(gB0 + kb, lB0 + bo);
            gld_lds16(gB1 + kb, lB1 + bo);
        }
        if (t + 2 < NT) {
            const int kb = (t + 2) * BK, ao = ((t + 2) % 3) * BUFE;
            gld_lds16(gA0 + kb, lA0 + ao);
            gld_lds16(gA1 + kb, lA1 + ao);
        }
        __builtin_amdgcn_sched_barrier(0);
        const u16* ac = ard + (t % 3) * BUFE;
        const u16* bc = brd + (t & 1) * BUFE;
        s16x8 bfr[4];
        #pragma unroll
        for (int j = 0; j < 4; j++) bfr[j] = *(const s16x8*)(bc + j*16*BK);
        __builtin_amdgcn_s_setprio(1);
        #pragma unroll
        for (int i = 0; i < 4; i++) {
            s16x8 af = *(const s16x8*)(ac + i*16*BK);
            #pragma unroll
            for (int j = 0; j < 4; j++) {
                if (SWAP)
                    acc[i][j] = __builtin_amdgcn_mfma_f32_16x16x32_bf16(bfr[j], af, acc[i][j], 0,0,0);
                else
                    acc[i][j] = __builtin_amdgcn_mfma_f32_16x16x32_bf16(af, bfr[j], acc[i][j], 0,0,0);
            }
        }
        __builtin_amdgcn_s_setprio(0);
        asm volatile("s_waitcnt lgkmcnt(0)" ::: "memory");
        __builtin_amdgcn_sched_barrier(0);
    }
}

// ---------------- GEMM kernels with fused epilogues ----------------
__global__ __launch_bounds__(256, 4) void k_gemm_bu(
    const u16* __restrict__ fx, const u16* __restrict__ Wb, u16* __restrict__ Bu)
{
    __shared__ __align__(16) u16 a_sh[3*BUFE], b_sh[2*BUFE];
    int mt, nt;
    swz_decode(gridDim.y, mt, nt);
    int m0 = mt * BM, n0 = nt * BN;
    f32x4 acc[4][4];
    gemm_core<false>(fx, CDIM, Wb, m0, n0, a_sh, b_sh, acc);
    int lane = threadIdx.x & 63, w = threadIdx.x >> 6;
    int t16 = lane & 15, quad = lane >> 4, wm = w >> 1, wn = w & 1;
    #pragma unroll
    for (int i = 0; i < 4; i++)
        #pragma unroll
        for (int j = 0; j < 4; j++)
            #pragma unroll
            for (int rr = 0; rr < 4; rr++) {
                int m = m0 + wm*64 + i*16 + quad*4 + rr;
                int n = n0 + wn*64 + j*16 + t16;
                Bu[(size_t)m * CDIM + n] = f2bf(acc[i][j][rr]);
            }
}

__global__ __launch_bounds__(256, 4) void k_gemm_y(
    const u16* __restrict__ xs, const u16* __restrict__ Wc,
    const u16* __restrict__ fx, const float* __restrict__ Dv, u16* __restrict__ y)
{
    __shared__ __align__(16) u16 a_sh[3*BUFE], b_sh[2*BUFE];
    int mt, nt;
    swz_decode(gridDim.y, mt, nt);
    int m0 = mt * BM, n0 = nt * BN;
    f32x4 acc[4][4];
    gemm_core<false>(xs, CDIM, Wc, m0, n0, a_sh, b_sh, acc);
    int lane = threadIdx.x & 63, w = threadIdx.x >> 6;
    int t16 = lane & 15, quad = lane >> 4, wm = w >> 1, wn = w & 1;
    float dv[4];
    #pragma unroll
    for (int j = 0; j < 4; j++) dv[j] = Dv[n0 + wn*64 + j*16 + t16];
    #pragma unroll
    for (int i = 0; i < 4; i++)
        #pragma unroll
        for (int j = 0; j < 4; j++)
            #pragma unroll
            for (int rr = 0; rr < 4; rr++) {
                int m = m0 + wm*64 + i*16 + quad*4 + rr;
                int n = n0 + wn*64 + j*16 + t16;
                float fxv = bf2f(fx[(size_t)m * CDIM + n]);
                float v = acc[i][j][rr] + dv[j] * fxv;
                y[(size_t)m * CDIM + n] = f2bf(gelu_fast(v) + fxv);
            }
}

// z-GEMM with fused GEGLU: block computes z1 cols [c0,c0+64) and z2 cols
// [384+c0, 384+c0+64); wn=1 waves gelu their z2 tile into LDS; wn=0 waves
// multiply and store zg[M,384] bf16.
__global__ __launch_bounds__(256, 4) void k_gemm_zg(
    const u16* __restrict__ fy, const u16* __restrict__ We, u16* __restrict__ zg)
{
    __shared__ __align__(16) u16 sh[5*BUFE];  // A tri-buf + B dbl-buf (40 KB); reused as exchange
    u16* a_sh = sh;
    u16* b_sh = sh + 3*BUFE;
    const int tid = threadIdx.x;
    const int w = tid >> 6, lane = tid & 63;
    const int t16 = lane & 15, quad = lane >> 4;
    const int wm = w >> 1, wn = w & 1;
    int mt, nt;
    swz_decode(gridDim.y, mt, nt);
    const int m0 = mt * BM;
    const int c0 = nt * 64;
    const int lr  = lane >> 2;
    const int cbg = (lane & 3) ^ ((lane >> 3) & 3);
    const u16* gA0 = fy + (size_t)(m0 + w*32 + lr) * CDIM + cbg*8;
    const u16* gA1 = gA0 + (size_t)16 * CDIM;
    int brow = c0 + w*32 + ((w >= 2) ? 320 : 0);   // w0,1: z1 rows; w2,3: z2 rows (384+c0+..)
    const u16* gB0 = We + (size_t)(brow + lr) * KD + cbg*8;
    const u16* gB1 = gB0 + (size_t)16 * KD;
    u16* lA0 = a_sh + (w*32) * BK;
    u16* lA1 = lA0 + 16*BK;
    u16* lB0 = b_sh + (w*32) * BK;
    u16* lB1 = lB0 + 16*BK;
    const int pos = (quad ^ ((t16 >> 1) & 3)) * 8;
    const u16* ard = a_sh + (wm*64 + t16) * BK + pos;
    const u16* brd = b_sh + (wn*64 + t16) * BK + pos;
    f32x4 acc[4][4];
    #pragma unroll
    for (int i = 0; i < 4; i++)
        #pragma unroll
        for (int j = 0; j < 4; j++) acc[i][j] = (f32x4){0.f,0.f,0.f,0.f};
    // prologue: A(0), B(0), A(1)
    gld_lds16(gA0, lA0);
    gld_lds16(gA1, lA1);
    gld_lds16(gB0, lB0);
    gld_lds16(gB1, lB1);
    gld_lds16(gA0 + BK, lA0 + BUFE);
    gld_lds16(gA1 + BK, lA1 + BUFE);
    #pragma unroll
    for (int t = 0; t < NT; ++t) {
        if (t < NT - 1) asm volatile("s_waitcnt vmcnt(2)" ::: "memory");
        else            asm volatile("s_waitcnt vmcnt(0)" ::: "memory");
        __builtin_amdgcn_s_barrier();
        __builtin_amdgcn_sched_barrier(0);
        if (t + 1 < NT) {
            const int kb = (t + 1) * BK, bo = ((t + 1) & 1) * BUFE;
            gld_lds16(gB0 + kb, lB0 + bo);
            gld_lds16(gB1 + kb, lB1 + bo);
        }
        if (t + 2 < NT) {
            const int kb = (t + 2) * BK, ao = ((t + 2) % 3) * BUFE;
            gld_lds16(gA0 + kb, lA0 + ao);
            gld_lds16(gA1 + kb, lA1 + ao);
        }
        __builtin_amdgcn_sched_barrier(0);
        const u16* ac = ard + (t % 3) * BUFE;
        const u16* bc = brd + (t & 1) * BUFE;
        s16x8 bfr[4];
        #pragma unroll
        for (int j = 0; j < 4; j++) bfr[j] = *(const s16x8*)(bc + j*16*BK);
        __builtin_amdgcn_s_setprio(1);
        #pragma unroll
        for (int i = 0; i < 4; i++) {
            s16x8 af = *(const s16x8*)(ac + i*16*BK);
            #pragma unroll
            for (int j = 0; j < 4; j++)
                acc[i][j] = __builtin_amdgcn_mfma_f32_16x16x32_bf16(af, bfr[j], acc[i][j], 0,0,0);
        }
        __builtin_amdgcn_s_setprio(0);
        asm volatile("s_waitcnt lgkmcnt(0)" ::: "memory");
        __builtin_amdgcn_sched_barrier(0);
    }
    __syncthreads();                       // all LDS frag reads done; reuse as exchange
    if (wn == 1) {
        #pragma unroll
        for (int i = 0; i < 4; i++)
            #pragma unroll
            for (int j = 0; j < 4; j++)
                #pragma unroll
                for (int rr = 0; rr < 4; rr++) {
                    int m = wm*64 + i*16 + quad*4 + rr;
                    int c = j*16 + t16;
                    sh[m*66 + c] = f2bf(gelu_fast(acc[i][j][rr]));
                }
    }
    __syncthreads();
    if (wn == 0) {
        #pragma unroll
        for (int i = 0; i < 4; i++)
            #pragma unroll
            for (int j = 0; j < 4; j++)
                #pragma unroll
                for (int rr = 0; rr < 4; rr++) {
                    int m = wm*64 + i*16 + quad*4 + rr;
                    int c = j*16 + t16;
                    float gv = bf2f(sh[m*66 + c]);
                    zg[(size_t)(m0 + m) * CDIM + c0 + c] = f2bf(acc[i][j][rr] * gv);
                }
    }
}

// out-GEMM. Epilogue: acc(+fy) dumped per 64-col half into a reused-LDS f32
// tile [64][130], then stored as 512-B contiguous rows (float4/lane) —
// replaces the old 64-B-segment scatter (out was 3.3 TB/s, ~half of BW).
__global__ __launch_bounds__(256, 4) void k_gemm_out(
    const u16* __restrict__ zg, const u16* __restrict__ Wd,
    const u16* __restrict__ fy, float* __restrict__ out)
{
    __shared__ __align__(16) u16 sh[5*BUFE];   // K-loop bufs; reused as f32 [64][130] (33.3 KB)
    u16* a_sh = sh;
    u16* b_sh = sh + 3*BUFE;
    int mt, nt;
    swz_decode(gridDim.y, mt, nt);
    int m0 = mt * BM, n0 = nt * BN;
    f32x4 acc[4][4];
    gemm_core<true>(zg, CDIM, Wd, m0, n0, a_sh, b_sh, acc);
    int tid = threadIdx.x;
    int lane = tid & 63, w = tid >> 6;
    int t16 = lane & 15, quad = lane >> 4, wm = w >> 1, wn = w & 1;
    int b = m0 >> 12;
    int lbase = m0 & 4095;
    float* exf = (float*)sh;                   // [64][130]
    __syncthreads();                           // K-loop LDS reads done (all waves)
    #pragma unroll
    for (int h = 0; h < 2; h++) {
        if (wn == h) {
            #pragma unroll
            for (int i = 0; i < 4; i++)
                #pragma unroll
                for (int j = 0; j < 4; j++)
                    #pragma unroll
                    for (int rr = 0; rr < 4; rr++) {
                        int nnl = j*16 + quad*4 + rr;          // 0..63 within half
                        int mml = wm*64 + i*16 + t16;          // 0..127
                        int nn  = n0 + h*64 + nnl;
                        int mm  = m0 + mml;
                        float fyv = bf2f(fy[(size_t)mm * CDIM + nn]);
                        exf[nnl*130 + mml] = acc[i][j][rr] + fyv;
                    }
        }
        __syncthreads();
        #pragma unroll
        for (int it = 0; it < 8; it++) {       // 64 rows x 32 float4 = 2048 slots
            int s = it * 256 + tid;
            int r = s >> 5, q = s & 31;
            float4 v = *(const float4*)(exf + r*130 + q*4);
            *(float4*)(out + ((size_t)(b * CDIM + n0 + h*64 + r)) * LDIM + lbase + q*4) = v;
        }
        __syncthreads();
    }
}

// ---------------- chunked complex scan over L (chunk=64, 64 chunks/b) ----------------
__global__ __launch_bounds__(192) void k_scan_a(
    const u16* __restrict__ Bu, const float* __restrict__ lam_bar,
    float* __restrict__ summ)
{
    int b = blockIdx.x >> 6, ch = blockIdx.x & 63;
    int p = threadIdx.x;
    float lr = lam_bar[2*p], li = lam_bar[2*p+1];
    float xr = 0.f, xi = 0.f;
    const u16* base = Bu + (size_t)(b * LDIM + ch * 64) * CDIM;
    #pragma unroll 8
    for (int i = 0; i < 64; i++) {
        float br = bf2f(base[(size_t)i * CDIM + p]);
        float bi = bf2f(base[(size_t)i * CDIM + PDIM + p]);
        float nr = lr * xr - li * xi + br;
        float ni = lr * xi + li * xr + bi;
        xr = nr; xi = ni;
    }
    size_t o = (size_t)(b * 64 + ch) * CDIM + p;
    summ[o] = xr;
    summ[o + PDIM] = xi;
}

// scan_b folded in: each block computes its own exclusive carry from the raw
// chunk sums (same recurrence, same c-ascending FP order as the old scan_b —
// bit-identical), then applies the in-chunk scan. Removes a 12-block launch
// and one full summ rewrite pass.
__global__ __launch_bounds__(192) void k_scan_c(
    u16* __restrict__ Bu, const float* __restrict__ lam_bar,
    const float* __restrict__ summ)
{
    int b = blockIdx.x >> 6, ch = blockIdx.x & 63;
    int p = threadIdx.x;
    float lr = lam_bar[2*p], li = lam_bar[2*p+1];
    float ar = lr, ai = li;
    #pragma unroll
    for (int s = 0; s < 6; s++) {       // lam_bar^64
        float nr = ar * ar - ai * ai, ni = 2.f * ar * ai;
        ar = nr; ai = ni;
    }
    float xr = 0.f, xi = 0.f;
    for (int c = 0; c < ch; c++) {
        size_t o = (size_t)(b * 64 + c) * CDIM + p;
        float sr = summ[o], si = summ[o + PDIM];
        float nr = ar * xr - ai * xi + sr;
        float ni = ar * xi + ai * xr + si;
        xr = nr; xi = ni;
    }
    u16* base = Bu + (size_t)(b * LDIM + ch * 64) * CDIM;
    #pragma unroll 8
    for (int i = 0; i < 64; i++) {
        float br = bf2f(base[(size_t)i * CDIM + p]);
        float bi = bf2f(base[(size_t)i * CDIM + PDIM + p]);
        float nr = lr * xr - li * xi + br;
        float ni = lr * xi + li * xr + bi;
        xr = nr; xi = ni;
        base[(size_t)i * CDIM + p] = f2bf(xr);
        base[(size_t)i * CDIM + PDIM + p] = f2bf(xi);
    }
}

// ---------------- LN2 (rows contiguous, bf16 in/out, packed u32 loads) -------
__global__ __launch_bounds__(256) void k_ln2(
    const u16* __restrict__ y, const float* __restrict__ g,
    const float* __restrict__ bb, u16* __restrict__ fy)
{
    int w = threadIdx.x >> 6, lane = threadIdx.x & 63;
    size_t m = (size_t)blockIdx.x * 4 + w;
    const u16* row = y + m * CDIM;
    float v[6];
    float sum = 0.f, sq = 0.f;
    #pragma unroll
    for (int i = 0; i < 3; i++) {
        u32 pk = *(const u32*)(row + lane * 2 + 128 * i);
        float a = bf2f((u16)pk), b2 = bf2f((u16)(pk >> 16));
        v[2*i] = a; v[2*i+1] = b2;
        sum += a + b2; sq += a*a + b2*b2;
    }
    #pragma unroll
    for (int o = 1; o < 64; o <<= 1) {
        sum += __shfl_xor(sum, o); sq += __shfl_xor(sq, o);
    }
    float mu  = sum * (1.0f / CDIM);
    float var = sq * (1.0f / CDIM) - mu * mu;
    float inv = rsqrtf(var + 1e-5f);
    u16* dst = fy + m * CDIM;
    #pragma unroll
    for (int i = 0; i < 3; i++) {
        int c = lane * 2 + 128 * i;
        float2 gv = *(const float2*)(g + c);
        float2 bv = *(const float2*)(bb + c);
        u16 o0 = f2bf((v[2*i]   - mu) * inv * gv.x + bv.x);
        u16 o1 = f2bf((v[2*i+1] - mu) * inv * gv.y + bv.y);
        *(u32*)(dst + c) = (u32)o0 | ((u32)o1 << 16);
    }
}

extern "C" void kernel_launch(void* const* d_in, const int* in_sizes, int n_in,
                              void* d_out, int out_size, void* d_ws, size_t ws_size,
                              hipStream_t stream)
{
    const float* x        = (const float*)d_in[0];
    const float* ln1_g    = (const float*)d_in[1];
    const float* ln1_b    = (const float*)d_in[2];
    const float* Lambda   = (const float*)d_in[3];
    const float* Bmat     = (const float*)d_in[4];
    const float* Cmat     = (const float*)d_in[5];
    const float* Dvec     = (const float*)d_in[6];
    const float* log_step = (const float*)d_in[7];
    const float* ln2_g    = (const float*)d_in[8];
    const float* ln2_b    = (const float*)d_in[9];
    const float* W_enc    = (const float*)d_in[10];
    const float* W_dec    = (const float*)d_in[11];

    char* ws = (char*)d_ws;
    const size_t HBF = (size_t)MDIM * CDIM * 2;    // 50,331,648 B (bf16 [M,384])
    u16* fx = (u16*)(ws);                          // fx bf16
    u16* fy = (u16*)(ws + HBF);                    // fy bf16
    u16* bu = (u16*)(ws + 2 * HBF);                // Bu/xs bf16 [M,384]
    u16* zg = (u16*)(ws + 2 * HBF);                // zg bf16 [M,384] (aliases bu; bu dead)
    char* wbase = ws + 3 * HBF;
    u16* Wb = (u16*)(wbase);
    u16* Wc = (u16*)(wbase + 294912);
    u16* We = (u16*)(wbase + 589824);
    u16* Wd = (u16*)(wbase + 1179648);
    float* lam_bar = (float*)(wbase + 1474560);
    float* summ    = (float*)(wbase + 1476096);    // 16*64*384 fp32
    u16* yb  = (u16*)d_out;                        // y bf16 scratch inside d_out
    float* out = (float*)d_out;

    k_setup<<<2305, 256, 0, stream>>>(Lambda, Bmat, Cmat, log_step, W_enc, W_dec,
                                      Wb, Wc, We, Wd, lam_bar);
    k_ln1<<<2048, 256, 0, stream>>>(x, ln1_g, ln1_b, fx);
    k_gemm_bu<<<dim3(512, 3), 256, 0, stream>>>(fx, Wb, bu);
    k_scan_a<<<1024, 192, 0, stream>>>(bu, lam_bar, summ);
    k_scan_c<<<1024, 192, 0, stream>>>(bu, lam_bar, summ);
    k_gemm_y<<<dim3(512, 3), 256, 0, stream>>>(bu, Wc, fx, Dvec, yb);
    k_ln2<<<16384, 256, 0, stream>>>(yb, ln2_g, ln2_b, fy);
    k_gemm_zg<<<dim3(512, 6), 256, 0, stream>>>(fy, We, zg);
    k_gemm_out<<<dim3(512, 3), 256, 0, stream>>>(zg, Wd, fy, out);
}

// Round 10
// 418.217 us; speedup vs baseline: 1.0570x; 1.0233x over previous
//
#include <hip/hip_runtime.h>
#include <hip/hip_bf16.h>
#include <math.h>

typedef __attribute__((ext_vector_type(4))) float f32x4;
typedef __attribute__((ext_vector_type(8))) short s16x8;
typedef unsigned short u16;
typedef unsigned int u32;

#define CDIM 384
#define PDIM 192
#define LDIM 4096
#define BSZ  16
#define MDIM 65536
#define KD   384
#define BM 128
#define BN 128
#define BK 32
#define NT (KD / BK)
#define BUFE (BM * BK)    // 4096 u16 = 8 KB per LDS buffer (A x3, B x2)

__device__ __forceinline__ u16 f2bf(float f) {
    u32 x = __float_as_uint(f);
    x += 0x7fffu + ((x >> 16) & 1u);
    return (u16)(x >> 16);
}
__device__ __forceinline__ float bf2f(u16 v) {
    return __uint_as_float(((u32)v) << 16);
}
__device__ __forceinline__ float gelu_exact(float x) {   // setup only (cold)
    return 0.5f * x * (1.0f + erff(x * 0.7071067811865476f));
}
// tanh-form gelu as a single sigmoid: x * sigmoid(1.59577*x*(1+0.044715x^2))
// max abs err vs exact gelu ~2e-3 — far under bf16 epilogue noise here.
__device__ __forceinline__ float gelu_fast(float x) {
    float w = -1.5957691216f * x * (1.0f + 0.044715f * x * x);
    return x / (1.0f + __expf(w));
}
__device__ __forceinline__ void gld_lds16(const u16* g, u16* l) {
    __builtin_amdgcn_global_load_lds(
        (const __attribute__((address_space(1))) void*)g,
        (__attribute__((address_space(3))) void*)l, 16, 0, 0);
}

// XCD-chunked swizzle: consecutive work-ids land on the same XCD, and work
// is decoded n-fastest so the NY blocks sharing an A-panel are consecutive
// (same-XCD L2 reuse of the A panel). Bijective: nwg % 8 == 0 here.
__device__ __forceinline__ void swz_decode(int NY, int& mt, int& nt) {
    int bid = blockIdx.x + gridDim.x * blockIdx.y;
    int nwg = gridDim.x * gridDim.y;
    int cpx = nwg >> 3;
    int work = (bid & 7) * cpx + (bid >> 3);
    mt = work / NY;
    nt = work - mt * NY;
}

// ---------------- setup: build bf16 weights + lam_bar ----------------
__global__ __launch_bounds__(256) void k_setup(
    const float* __restrict__ Lambda, const float* __restrict__ Bmat,
    const float* __restrict__ Cmat, const float* __restrict__ log_step,
    const float* __restrict__ W_enc, const float* __restrict__ W_dec,
    u16* __restrict__ Wb, u16* __restrict__ Wc, u16* __restrict__ We,
    u16* __restrict__ Wd, float* __restrict__ lam_bar)
{
    int idx = blockIdx.x * 256 + threadIdx.x;
    if (idx < 73728) {                       // Wb: B_bar^T rows [2P][C]
        int p = idx / CDIM, c = idx % CDIM;
        float st  = expf(log_step[p]);
        float lre = Lambda[2*p], lim = Lambda[2*p+1];
        float el  = expf(lre * st);
        float lbr = el * cosf(lim * st);
        float lbi = el * sinf(lim * st);
        float dd  = lre*lre + lim*lim;
        float a = lbr - 1.0f, b = lbi;
        float cr = (a * lre + b * lim) / dd; // (lam_bar-1)/lam
        float ci = (b * lre - a * lim) / dd;
        float Br = Bmat[2*(p*CDIM + c)], Bi = Bmat[2*(p*CDIM + c) + 1];
        Wb[p*KD + c]          = f2bf(cr*Br - ci*Bi);
        Wb[(PDIM + p)*KD + c] = f2bf(cr*Bi + ci*Br);
    } else if (idx < 147456) {               // Wc: [C][2P], 2*mask folded, -im
        int e = idx - 73728;
        int h = e / PDIM, p = e % PDIM;
        float st  = expf(log_step[p]);
        float lim = Lambda[2*p+1];
        float freq = st * fabsf(lim) / 6.283185307179586f;
        float sc = (freq < 0.25f) ? 2.0f : 0.0f;
        Wc[h*KD + p]        = f2bf( sc * Cmat[2*(h*PDIM + p)]);
        Wc[h*KD + PDIM + p] = f2bf(-sc * Cmat[2*(h*PDIM + p) + 1]);
    } else if (idx < 442368) {               // We: W_enc [768][384]
        int e = idx - 147456;
        We[e] = f2bf(W_enc[e]);
    } else if (idx < 589824) {               // Wd: W_dec [384][384]
        int e = idx - 442368;
        Wd[e] = f2bf(W_dec[e]);
    } else if (idx < 590016) {               // lam_bar [P][2]
        int p = idx - 589824;
        float st  = expf(log_step[p]);
        float lre = Lambda[2*p], lim = Lambda[2*p+1];
        float el  = expf(lre * st);
        lam_bar[2*p]   = el * cosf(lim * st);
        lam_bar[2*p+1] = el * sinf(lim * st);
    }
}

// ---------------- LN1 + transpose: x[B,C,L] fp32 -> fx[M,C] bf16 ----------------
#define LNS 388
__global__ __launch_bounds__(256) void k_ln1(
    const float* __restrict__ x, const float* __restrict__ g,
    const float* __restrict__ bb, u16* __restrict__ fx)
{
    __shared__ float tile[32 * LNS];
    __shared__ float mu_sh[32], inv_sh[32];
    int b  = blockIdx.x >> 7;
    int l0 = (blockIdx.x & 127) * 32;
    int tid = threadIdx.x;
    const float* src = x + ((size_t)b * CDIM) * LDIM + l0;
    #pragma unroll
    for (int it = 0; it < 12; it++) {
        int s = it * 256 + tid;           // 3072 float4 slots
        int ch = s >> 3, k4 = s & 7;
        float4 v = *(const float4*)(src + (size_t)ch * LDIM + k4 * 4);
        float* t0 = tile + (k4 * 4) * LNS + ch;
        t0[0]       = v.x;
        t0[LNS]     = v.y;
        t0[2*LNS]   = v.z;
        t0[3*LNS]   = v.w;
    }
    __syncthreads();
    int j = tid >> 3, k = tid & 7;        // j: l-row 0..31, k: 8-way c-split
    float sum = 0.f, sq = 0.f;
    #pragma unroll
    for (int m = 0; m < 12; m++) {
        float4 v = *(const float4*)(tile + j * LNS + (k + 8*m) * 4);
        sum += v.x + v.y + v.z + v.w;
        sq  += v.x*v.x + v.y*v.y + v.z*v.z + v.w*v.w;
    }
    sum += __shfl_xor(sum, 1); sq += __shfl_xor(sq, 1);
    sum += __shfl_xor(sum, 2); sq += __shfl_xor(sq, 2);
    sum += __shfl_xor(sum, 4); sq += __shfl_xor(sq, 4);
    float mu  = sum * (1.0f / CDIM);
    float var = sq * (1.0f / CDIM) - mu * mu;
    float inv = rsqrtf(var + 1e-5f);
    if (k == 0) { mu_sh[j] = mu; inv_sh[j] = inv; }
    __syncthreads();
    u16* dst = fx + ((size_t)(b * LDIM + l0)) * CDIM;
    #pragma unroll
    for (int it = 0; it < 12; it++) {
        int s  = it * 256 + tid;          // 3072 slots of 4 channels
        int cq = s % 96, jj = s / 96;
        int c  = cq * 4;
        float m2 = mu_sh[jj], iv = inv_sh[jj];
        float4 gv = *(const float4*)(g + c);
        float4 bv = *(const float4*)(bb + c);
        float4 v  = *(const float4*)(tile + jj * LNS + c);
        ushort4 o;
        o.x = f2bf((v.x - m2) * iv * gv.x + bv.x);
        o.y = f2bf((v.y - m2) * iv * gv.y + bv.y);
        o.z = f2bf((v.z - m2) * iv * gv.z + bv.z);
        o.w = f2bf((v.w - m2) * iv * gv.w + bv.w);
        *(ushort4*)(dst + (size_t)jj * CDIM + c) = o;
    }
}

// ------------- 128x128 GEMM core: A 3-buf / B 2-buf, reg-slim, 4 waves/SIMD ---
// r7 structure (best measured). Queue discipline: prologue A(0):2, B(0):2,
// A(1):2; per-iter issue B(t+1):2 then A(t+2):2. At iter-t wait the queue is
// [A(t),B(t),A(t+1)] -> s_waitcnt vmcnt(2) retires tile t while A(t+1) rides
// the barrier (B 1-step cover: L2-hot weights; A 2-step: L3-latency stream).
// Trailing lgkmcnt(0)+sched_barrier(0) closes the rule-18 MFMA-sink race
// (each buffer is rewritten one iteration after its last ds_read).
template<bool SWAP>
__device__ __forceinline__ void gemm_core(
    const u16* __restrict__ A, int lda, const u16* __restrict__ Bw,
    int m0, int n0, u16* a_sh, u16* b_sh, f32x4 acc[4][4])
{
    const int tid  = threadIdx.x;
    const int w    = tid >> 6, lane = tid & 63;
    const int t16  = lane & 15, quad = lane >> 4;
    const int wm   = w >> 1,   wn   = w & 1;
    const int lr  = lane >> 2;                       // row within 16-row issue
    const int cbg = (lane & 3) ^ ((lane >> 3) & 3);  // swizzled col-block
    const u16* gA0 = A  + (size_t)(m0 + w*32 + lr) * lda + cbg*8;
    const u16* gA1 = gA0 + (size_t)16 * lda;
    const u16* gB0 = Bw + (size_t)(n0 + w*32 + lr) * KD + cbg*8;
    const u16* gB1 = gB0 + (size_t)16 * KD;
    u16* lA0 = a_sh + (w*32) * BK;                   // wave-uniform LDS bases
    u16* lA1 = lA0 + 16*BK;
    u16* lB0 = b_sh + (w*32) * BK;
    u16* lB1 = lB0 + 16*BK;
    const int pos = (quad ^ ((t16 >> 1) & 3)) * 8;
    const u16* ard = a_sh + (wm*64 + t16) * BK + pos;
    const u16* brd = b_sh + (wn*64 + t16) * BK + pos;
    #pragma unroll
    for (int i = 0; i < 4; i++)
        #pragma unroll
        for (int j = 0; j < 4; j++) acc[i][j] = (f32x4){0.f,0.f,0.f,0.f};
    // prologue: A(0), B(0), A(1) — queue order matters for vmcnt counting
    gld_lds16(gA0, lA0);
    gld_lds16(gA1, lA1);
    gld_lds16(gB0, lB0);
    gld_lds16(gB1, lB1);
    gld_lds16(gA0 + BK, lA0 + BUFE);
    gld_lds16(gA1 + BK, lA1 + BUFE);
    #pragma unroll
    for (int t = 0; t < NT; ++t) {
        if (t < NT - 1) asm volatile("s_waitcnt vmcnt(2)" ::: "memory");
        else            asm volatile("s_waitcnt vmcnt(0)" ::: "memory");
        __builtin_amdgcn_s_barrier();
        __builtin_amdgcn_sched_barrier(0);
        if (t + 1 < NT) {                 // B(t+1) first: stays older than A(t+2)
            const int kb = (t + 1) * BK, bo = ((t + 1) & 1) * BUFE;
            gld_lds16(gB0 + kb, lB0 + bo);
            gld_lds16(gB1 + kb, lB1 + bo);
        }
        if (t + 2 < NT) {
            const int kb = (t + 2) * BK, ao = ((t + 2) % 3) * BUFE;
            gld_lds16(gA0 + kb, lA0 + ao);
            gld_lds16(gA1 + kb, lA1 + ao);
        }
        __builtin_amdgcn_sched_barrier(0);
        const u16* ac = ard + (t % 3) * BUFE;
        const u16* bc = brd + (t & 1) * BUFE;
        s16x8 bfr[4];
        #pragma unroll
        for (int j = 0; j < 4; j++) bfr[j] = *(const s16x8*)(bc + j*16*BK);
        __builtin_amdgcn_s_setprio(1);
        #pragma unroll
        for (int i = 0; i < 4; i++) {
            s16x8 af = *(const s16x8*)(ac + i*16*BK);
            #pragma unroll
            for (int j = 0; j < 4; j++) {
                if (SWAP)
                    acc[i][j] = __builtin_amdgcn_mfma_f32_16x16x32_bf16(bfr[j], af, acc[i][j], 0,0,0);
                else
                    acc[i][j] = __builtin_amdgcn_mfma_f32_16x16x32_bf16(af, bfr[j], acc[i][j], 0,0,0);
            }
        }
        __builtin_amdgcn_s_setprio(0);
        asm volatile("s_waitcnt lgkmcnt(0)" ::: "memory");
        __builtin_amdgcn_sched_barrier(0);
    }
}

// ---------------- GEMM kernels with fused epilogues ----------------
__global__ __launch_bounds__(256, 4) void k_gemm_bu(
    const u16* __restrict__ fx, const u16* __restrict__ Wb, u16* __restrict__ Bu)
{
    __shared__ __align__(16) u16 a_sh[3*BUFE], b_sh[2*BUFE];
    int mt, nt;
    swz_decode(gridDim.y, mt, nt);
    int m0 = mt * BM, n0 = nt * BN;
    f32x4 acc[4][4];
    gemm_core<false>(fx, CDIM, Wb, m0, n0, a_sh, b_sh, acc);
    int lane = threadIdx.x & 63, w = threadIdx.x >> 6;
    int t16 = lane & 15, quad = lane >> 4, wm = w >> 1, wn = w & 1;
    #pragma unroll
    for (int i = 0; i < 4; i++)
        #pragma unroll
        for (int j = 0; j < 4; j++)
            #pragma unroll
            for (int rr = 0; rr < 4; rr++) {
                int m = m0 + wm*64 + i*16 + quad*4 + rr;
                int n = n0 + wn*64 + j*16 + t16;
                Bu[(size_t)m * CDIM + n] = f2bf(acc[i][j][rr]);
            }
}

__global__ __launch_bounds__(256, 4) void k_gemm_y(
    const u16* __restrict__ xs, const u16* __restrict__ Wc,
    const u16* __restrict__ fx, const float* __restrict__ Dv, u16* __restrict__ y)
{
    __shared__ __align__(16) u16 a_sh[3*BUFE], b_sh[2*BUFE];
    int mt, nt;
    swz_decode(gridDim.y, mt, nt);
    int m0 = mt * BM, n0 = nt * BN;
    f32x4 acc[4][4];
    gemm_core<false>(xs, CDIM, Wc, m0, n0, a_sh, b_sh, acc);
    int lane = threadIdx.x & 63, w = threadIdx.x >> 6;
    int t16 = lane & 15, quad = lane >> 4, wm = w >> 1, wn = w & 1;
    float dv[4];
    #pragma unroll
    for (int j = 0; j < 4; j++) dv[j] = Dv[n0 + wn*64 + j*16 + t16];
    #pragma unroll
    for (int i = 0; i < 4; i++)
        #pragma unroll
        for (int j = 0; j < 4; j++)
            #pragma unroll
            for (int rr = 0; rr < 4; rr++) {
                int m = m0 + wm*64 + i*16 + quad*4 + rr;
                int n = n0 + wn*64 + j*16 + t16;
                float fxv = bf2f(fx[(size_t)m * CDIM + n]);
                float v = acc[i][j][rr] + dv[j] * fxv;
                y[(size_t)m * CDIM + n] = f2bf(gelu_fast(v) + fxv);
            }
}

// z-GEMM with fused GEGLU: block computes z1 cols [c0,c0+64) and z2 cols
// [384+c0, 384+c0+64); wn=1 waves gelu their z2 tile into LDS; wn=0 waves
// multiply and store zg[M,384] bf16.
__global__ __launch_bounds__(256, 4) void k_gemm_zg(
    const u16* __restrict__ fy, const u16* __restrict__ We, u16* __restrict__ zg)
{
    __shared__ __align__(16) u16 sh[5*BUFE];  // A tri-buf + B dbl-buf (40 KB); reused as exchange
    u16* a_sh = sh;
    u16* b_sh = sh + 3*BUFE;
    const int tid = threadIdx.x;
    const int w = tid >> 6, lane = tid & 63;
    const int t16 = lane & 15, quad = lane >> 4;
    const int wm = w >> 1, wn = w & 1;
    int mt, nt;
    swz_decode(gridDim.y, mt, nt);
    const int m0 = mt * BM;
    const int c0 = nt * 64;
    const int lr  = lane >> 2;
    const int cbg = (lane & 3) ^ ((lane >> 3) & 3);
    const u16* gA0 = fy + (size_t)(m0 + w*32 + lr) * CDIM + cbg*8;
    const u16* gA1 = gA0 + (size_t)16 * CDIM;
    int brow = c0 + w*32 + ((w >= 2) ? 320 : 0);   // w0,1: z1 rows; w2,3: z2 rows (384+c0+..)
    const u16* gB0 = We + (size_t)(brow + lr) * KD + cbg*8;
    const u16* gB1 = gB0 + (size_t)16 * KD;
    u16* lA0 = a_sh + (w*32) * BK;
    u16* lA1 = lA0 + 16*BK;
    u16* lB0 = b_sh + (w*32) * BK;
    u16* lB1 = lB0 + 16*BK;
    const int pos = (quad ^ ((t16 >> 1) & 3)) * 8;
    const u16* ard = a_sh + (wm*64 + t16) * BK + pos;
    const u16* brd = b_sh + (wn*64 + t16) * BK + pos;
    f32x4 acc[4][4];
    #pragma unroll
    for (int i = 0; i < 4; i++)
        #pragma unroll
        for (int j = 0; j < 4; j++) acc[i][j] = (f32x4){0.f,0.f,0.f,0.f};
    // prologue: A(0), B(0), A(1)
    gld_lds16(gA0, lA0);
    gld_lds16(gA1, lA1);
    gld_lds16(gB0, lB0);
    gld_lds16(gB1, lB1);
    gld_lds16(gA0 + BK, lA0 + BUFE);
    gld_lds16(gA1 + BK, lA1 + BUFE);
    #pragma unroll
    for (int t = 0; t < NT; ++t) {
        if (t < NT - 1) asm volatile("s_waitcnt vmcnt(2)" ::: "memory");
        else            asm volatile("s_waitcnt vmcnt(0)" ::: "memory");
        __builtin_amdgcn_s_barrier();
        __builtin_amdgcn_sched_barrier(0);
        if (t + 1 < NT) {
            const int kb = (t + 1) * BK, bo = ((t + 1) & 1) * BUFE;
            gld_lds16(gB0 + kb, lB0 + bo);
            gld_lds16(gB1 + kb, lB1 + bo);
        }
        if (t + 2 < NT) {
            const int kb = (t + 2) * BK, ao = ((t + 2) % 3) * BUFE;
            gld_lds16(gA0 + kb, lA0 + ao);
            gld_lds16(gA1 + kb, lA1 + ao);
        }
        __builtin_amdgcn_sched_barrier(0);
        const u16* ac = ard + (t % 3) * BUFE;
        const u16* bc = brd + (t & 1) * BUFE;
        s16x8 bfr[4];
        #pragma unroll
        for (int j = 0; j < 4; j++) bfr[j] = *(const s16x8*)(bc + j*16*BK);
        __builtin_amdgcn_s_setprio(1);
        #pragma unroll
        for (int i = 0; i < 4; i++) {
            s16x8 af = *(const s16x8*)(ac + i*16*BK);
            #pragma unroll
            for (int j = 0; j < 4; j++)
                acc[i][j] = __builtin_amdgcn_mfma_f32_16x16x32_bf16(af, bfr[j], acc[i][j], 0,0,0);
        }
        __builtin_amdgcn_s_setprio(0);
        asm volatile("s_waitcnt lgkmcnt(0)" ::: "memory");
        __builtin_amdgcn_sched_barrier(0);
    }
    __syncthreads();                       // all LDS frag reads done; reuse as exchange
    if (wn == 1) {
        #pragma unroll
        for (int i = 0; i < 4; i++)
            #pragma unroll
            for (int j = 0; j < 4; j++)
                #pragma unroll
                for (int rr = 0; rr < 4; rr++) {
                    int m = wm*64 + i*16 + quad*4 + rr;
                    int c = j*16 + t16;
                    sh[m*66 + c] = f2bf(gelu_fast(acc[i][j][rr]));
                }
    }
    __syncthreads();
    if (wn == 0) {
        #pragma unroll
        for (int i = 0; i < 4; i++)
            #pragma unroll
            for (int j = 0; j < 4; j++)
                #pragma unroll
                for (int rr = 0; rr < 4; rr++) {
                    int m = wm*64 + i*16 + quad*4 + rr;
                    int c = j*16 + t16;
                    float gv = bf2f(sh[m*66 + c]);
                    zg[(size_t)(m0 + m) * CDIM + c0 + c] = f2bf(acc[i][j][rr] * gv);
                }
    }
}

// out-GEMM. Epilogue: acc(+fy) dumped per 64-col half into a reused-LDS f32
// tile [64][130], then stored as 512-B contiguous rows (float4/lane) —
// replaces the old 64-B-segment scatter (out was 3.3 TB/s, ~half of BW).
__global__ __launch_bounds__(256, 4) void k_gemm_out(
    const u16* __restrict__ zg, const u16* __restrict__ Wd,
    const u16* __restrict__ fy, float* __restrict__ out)
{
    __shared__ __align__(16) u16 sh[5*BUFE];   // K-loop bufs; reused as f32 [64][130] (33.3 KB)
    u16* a_sh = sh;
    u16* b_sh = sh + 3*BUFE;
    int mt, nt;
    swz_decode(gridDim.y, mt, nt);
    int m0 = mt * BM, n0 = nt * BN;
    f32x4 acc[4][4];
    gemm_core<true>(zg, CDIM, Wd, m0, n0, a_sh, b_sh, acc);
    int tid = threadIdx.x;
    int lane = tid & 63, w = tid >> 6;
    int t16 = lane & 15, quad = lane >> 4, wm = w >> 1, wn = w & 1;
    int b = m0 >> 12;
    int lbase = m0 & 4095;
    float* exf = (float*)sh;                   // [64][130]
    __syncthreads();                           // K-loop LDS reads done (all waves)
    #pragma unroll
    for (int h = 0; h < 2; h++) {
        if (wn == h) {
            #pragma unroll
            for (int i = 0; i < 4; i++)
                #pragma unroll
                for (int j = 0; j < 4; j++)
                    #pragma unroll
                    for (int rr = 0; rr < 4; rr++) {
                        int nnl = j*16 + quad*4 + rr;          // 0..63 within half
                        int mml = wm*64 + i*16 + t16;          // 0..127
                        int nn  = n0 + h*64 + nnl;
                        int mm  = m0 + mml;
                        float fyv = bf2f(fy[(size_t)mm * CDIM + nn]);
                        exf[nnl*130 + mml] = acc[i][j][rr] + fyv;
                    }
        }
        __syncthreads();
        #pragma unroll
        for (int it = 0; it < 8; it++) {       // 64 rows x 32 float4 = 2048 slots
            int s = it * 256 + tid;
            int r = s >> 5, q = s & 31;
            float4 v = *(const float4*)(exf + r*130 + q*4);
            *(float4*)(out + ((size_t)(b * CDIM + n0 + h*64 + r)) * LDIM + lbase + q*4) = v;
        }
        __syncthreads();
    }
}

// ---------------- chunked complex scan over L (chunk=64, 64 chunks/b) ----------------
__global__ __launch_bounds__(192) void k_scan_a(
    const u16* __restrict__ Bu, const float* __restrict__ lam_bar,
    float* __restrict__ summ)
{
    int b = blockIdx.x >> 6, ch = blockIdx.x & 63;
    int p = threadIdx.x;
    float lr = lam_bar[2*p], li = lam_bar[2*p+1];
    float xr = 0.f, xi = 0.f;
    const u16* base = Bu + (size_t)(b * LDIM + ch * 64) * CDIM;
    #pragma unroll 8
    for (int i = 0; i < 64; i++) {
        float br = bf2f(base[(size_t)i * CDIM + p]);
        float bi = bf2f(base[(size_t)i * CDIM + PDIM + p]);
        float nr = lr * xr - li * xi + br;
        float ni = lr * xi + li * xr + bi;
        xr = nr; xi = ni;
    }
    size_t o = (size_t)(b * 64 + ch) * CDIM + p;
    summ[o] = xr;
    summ[o + PDIM] = xi;
}

__global__ __launch_bounds__(256) void k_scan_b(
    const float* __restrict__ lam_bar, float* __restrict__ summ)
{
    int id = blockIdx.x * 256 + threadIdx.x;
    if (id >= BSZ * PDIM) return;
    int b = id / PDIM, p = id % PDIM;
    float ar = lam_bar[2*p], ai = lam_bar[2*p+1];
    #pragma unroll
    for (int s = 0; s < 6; s++) {       // lam_bar^64
        float nr = ar * ar - ai * ai, ni = 2.f * ar * ai;
        ar = nr; ai = ni;
    }
    float cr = 0.f, ci = 0.f;
    #pragma unroll 4
    for (int ch = 0; ch < 64; ch++) {
        size_t o = (size_t)(b * 64 + ch) * CDIM + p;
        float sr = summ[o], si = summ[o + PDIM];
        summ[o] = cr; summ[o + PDIM] = ci;   // exclusive carry-in
        float nr = ar * cr - ai * ci + sr;
        float ni = ar * ci + ai * cr + si;
        cr = nr; ci = ni;
    }
}

__global__ __launch_bounds__(192) void k_scan_c(
    u16* __restrict__ Bu, const float* __restrict__ lam_bar,
    const float* __restrict__ summ)
{
    int b = blockIdx.x >> 6, ch = blockIdx.x & 63;
    int p = threadIdx.x;
    float lr = lam_bar[2*p], li = lam_bar[2*p+1];
    size_t oc = (size_t)(b * 64 + ch) * CDIM + p;
    float xr = summ[oc], xi = summ[oc + PDIM];
    u16* base = Bu + (size_t)(b * LDIM + ch * 64) * CDIM;
    #pragma unroll 8
    for (int i = 0; i < 64; i++) {
        float br = bf2f(base[(size_t)i * CDIM + p]);
        float bi = bf2f(base[(size_t)i * CDIM + PDIM + p]);
        float nr = lr * xr - li * xi + br;
        float ni = lr * xi + li * xr + bi;
        xr = nr; xi = ni;
        base[(size_t)i * CDIM + p] = f2bf(xr);
        base[(size_t)i * CDIM + PDIM + p] = f2bf(xi);
    }
}

// ---------------- LN2 (rows contiguous, bf16 in/out, packed u32 loads) -------
__global__ __launch_bounds__(256) void k_ln2(
    const u16* __restrict__ y, const float* __restrict__ g,
    const float* __restrict__ bb, u16* __restrict__ fy)
{
    int w = threadIdx.x >> 6, lane = threadIdx.x & 63;
    size_t m = (size_t)blockIdx.x * 4 + w;
    const u16* row = y + m * CDIM;
    float v[6];
    float sum = 0.f, sq = 0.f;
    #pragma unroll
    for (int i = 0; i < 3; i++) {
        u32 pk = *(const u32*)(row + lane * 2 + 128 * i);
        float a = bf2f((u16)pk), b2 = bf2f((u16)(pk >> 16));
        v[2*i] = a; v[2*i+1] = b2;
        sum += a + b2; sq += a*a + b2*b2;
    }
    #pragma unroll
    for (int o = 1; o < 64; o <<= 1) {
        sum += __shfl_xor(sum, o); sq += __shfl_xor(sq, o);
    }
    float mu  = sum * (1.0f / CDIM);
    float var = sq * (1.0f / CDIM) - mu * mu;
    float inv = rsqrtf(var + 1e-5f);
    u16* dst = fy + m * CDIM;
    #pragma unroll
    for (int i = 0; i < 3; i++) {
        int c = lane * 2 + 128 * i;
        float2 gv = *(const float2*)(g + c);
        float2 bv = *(const float2*)(bb + c);
        u16 o0 = f2bf((v[2*i]   - mu) * inv * gv.x + bv.x);
        u16 o1 = f2bf((v[2*i+1] - mu) * inv * gv.y + bv.y);
        *(u32*)(dst + c) = (u32)o0 | ((u32)o1 << 16);
    }
}

extern "C" void kernel_launch(void* const* d_in, const int* in_sizes, int n_in,
                              void* d_out, int out_size, void* d_ws, size_t ws_size,
                              hipStream_t stream)
{
    const float* x        = (const float*)d_in[0];
    const float* ln1_g    = (const float*)d_in[1];
    const float* ln1_b    = (const float*)d_in[2];
    const float* Lambda   = (const float*)d_in[3];
    const float* Bmat     = (const float*)d_in[4];
    const float* Cmat     = (const float*)d_in[5];
    const float* Dvec     = (const float*)d_in[6];
    const float* log_step = (const float*)d_in[7];
    const float* ln2_g    = (const float*)d_in[8];
    const float* ln2_b    = (const float*)d_in[9];
    const float* W_enc    = (const float*)d_in[10];
    const float* W_dec    = (const float*)d_in[11];

    char* ws = (char*)d_ws;
    const size_t HBF = (size_t)MDIM * CDIM * 2;    // 50,331,648 B (bf16 [M,384])
    u16* fx = (u16*)(ws);                          // fx bf16
    u16* fy = (u16*)(ws + HBF);                    // fy bf16
    u16* bu = (u16*)(ws + 2 * HBF);                // Bu/xs bf16 [M,384]
    u16* zg = (u16*)(ws + 2 * HBF);                // zg bf16 [M,384] (aliases bu; bu dead)
    char* wbase = ws + 3 * HBF;
    u16* Wb = (u16*)(wbase);
    u16* Wc = (u16*)(wbase + 294912);
    u16* We = (u16*)(wbase + 589824);
    u16* Wd = (u16*)(wbase + 1179648);
    float* lam_bar = (float*)(wbase + 1474560);
    float* summ    = (float*)(wbase + 1476096);    // 16*64*384 fp32
    u16* yb  = (u16*)d_out;                        // y bf16 scratch inside d_out
    float* out = (float*)d_out;

    k_setup<<<2305, 256, 0, stream>>>(Lambda, Bmat, Cmat, log_step, W_enc, W_dec,
                                      Wb, Wc, We, Wd, lam_bar);
    k_ln1<<<2048, 256, 0, stream>>>(x, ln1_g, ln1_b, fx);
    k_gemm_bu<<<dim3(512, 3), 256, 0, stream>>>(fx, Wb, bu);
    k_scan_a<<<1024, 192, 0, stream>>>(bu, lam_bar, summ);
    k_scan_b<<<12, 256, 0, stream>>>(lam_bar, summ);
    k_scan_c<<<1024, 192, 0, stream>>>(bu, lam_bar, summ);
    k_gemm_y<<<dim3(512, 3), 256, 0, stream>>>(bu, Wc, fx, Dvec, yb);
    k_ln2<<<16384, 256, 0, stream>>>(yb, ln2_g, ln2_b, fy);
    k_gemm_zg<<<dim3(512, 6), 256, 0, stream>>>(fy, We, zg);
    k_gemm_out<<<dim3(512, 3), 256, 0, stream>>>(zg, Wd, fy, out);
}